// Round 11
// baseline (2000.857 us; speedup 1.0000x reference)
//
#include <hip/hip_runtime.h>
#include <stdint.h>

typedef __attribute__((ext_vector_type(8))) short short8;
typedef __attribute__((ext_vector_type(4))) float f32x4;
typedef unsigned short u16;

// ---- helpers ----
__device__ __forceinline__ u16 f2bf(float f) {
  uint32_t u = __builtin_bit_cast(uint32_t, f);
  u = (u + 0x7FFFu + ((u >> 16) & 1u)) >> 16;
  return (u16)u;
}
__device__ __forceinline__ float bf2f(u16 h) {
  uint32_t u = ((uint32_t)h) << 16;
  return __builtin_bit_cast(float, u);
}
__device__ __forceinline__ void lds16(const u16* g, u16* l) {
  __builtin_amdgcn_global_load_lds(
      (const __attribute__((address_space(1))) void*)g,
      (__attribute__((address_space(3))) void*)l, 16, 0, 0);
}
// LDS XOR swizzles on u16 indices (16B granule): involutions.
__device__ __forceinline__ int sw256(int i) { return i ^ (((i >> 7) & 7) << 3); }
__device__ __forceinline__ int sw128(int i) { return i ^ (((i >> 6) & 7) << 3); }
// tile-row swizzles: 64-u16-wide rows: flip slot bits[5:3] by row&7
__device__ __forceinline__ int swzA64(int i) { return i ^ (((i >> 6) & 7) << 3); }
// 32-u16-wide rows: flip slot bits[4:3] by (row>>1)&3
__device__ __forceinline__ int swzA32(int i) { return i ^ (((i >> 6) & 3) << 3); }

#define SB0() __builtin_amdgcn_sched_barrier(0)
#define BAR() __builtin_amdgcn_s_barrier()
#define LGKM0() do { asm volatile("s_waitcnt lgkmcnt(0)" ::: "memory"); SB0(); } while (0)
#define VM(n) asm volatile("s_waitcnt vmcnt(" #n ")" ::: "memory")

// ---- split f32 -> bf16 hi (+ optional lo) ----
__global__ void split_kernel(const float* __restrict__ in, u16* __restrict__ hi,
                             u16* __restrict__ lo, int n) {
  int i = blockIdx.x * blockDim.x + threadIdx.x;
  int stride = gridDim.x * blockDim.x;
  for (; i < n; i += stride) {
    float v = in[i];
    u16 h = f2bf(v);
    hi[i] = h;
    if (lo) lo[i] = f2bf(v - bf2f(h));
  }
}

// ==== 128x256 GEMM, 2-blocks/CU co-residency (m114 cross-block overlap) ====
// Grid 512 (2 blocks/CU), single-buffered 48KB LDS, __launch_bounds__(512,4)
// caps VGPR at 128 -> 4 waves/SIMD. 8 waves (2M x 4N), wave tile 64x64
// (acc = 64 VGPR). Per K-tile: RD-all -> lgkm(0) -> barrier (reads drained,
// buffer free) -> stage next tile into SAME buffer -> pure-register MFMA
// passes (stage DMA flies underneath) -> vm(0) -> barrier. Intra-block the
// read-drain serializes, but the co-resident second block is in its MFMA
// phase then -> LDS and MFMA pipes overlap ACROSS blocks.
// SPLIT=1: BK=64. SPLIT=3: BK=32, passes Ah*Bh, Ah*Bl, Al*Bh (bf16x3).
// EPI 0: bf16 (b,h,t,d), *qscale | EPI 1: sign->+-1 bf16 (b,h,t,d) | EPI 2: f32 MxN
template<int SPLIT, int EPI>
__global__ __launch_bounds__(512, 4) void gemm8p(
    const u16* __restrict__ Ahi, const u16* __restrict__ Alo,
    const u16* __restrict__ Bhi, const u16* __restrict__ Blo,
    u16* __restrict__ outb, float* __restrict__ outf,
    int Mdim, int Ndim, int Kdim)
{
  constexpr int BK  = (SPLIT > 1) ? 32 : 64;
  constexpr int ASZ = 128 * BK;                  // u16: 4096 / 8192
  constexpr int BSZ = 256 * BK;                  // u16: 8192 / 16384
  constexpr int AOFF_H = 0;
  constexpr int AOFF_L = ASZ;                    // SPLIT=3 only
  constexpr int BOFF_H = (SPLIT > 1) ? 2*ASZ : ASZ;
  constexpr int BOFF_L = BOFF_H + BSZ;           // SPLIT=3 only
  __shared__ __align__(16) u16 smem[24576];      // 48 KiB both variants

  const int t = threadIdx.x, l = t & 63;
  const int w = t >> 6;
  const int wm = w >> 2, wn = w & 3;             // 2M x 4N
  const int fr = l & 15, fs = l >> 4;
  // XCD-bijective block swizzle (512 blocks % 8 == 0)
  const int sb = (blockIdx.x & 7) * 64 + (blockIdx.x >> 3);
  const int m0 = (sb >> 3) * 128, n0 = (sb & 7) * 256;
  const int NT = Kdim / BK;

  // stage `nr` 8KB rounds of matrix `src` (rowsxBK) for K-tile kt.
  auto STM = [&](const u16* src, int g0, int moff, int nr, int kt) {
#pragma unroll
    for (int r = 0; r < nr; r++) {
      int d = r * 4096 + t * 8;
      int row, scol;
      if constexpr (SPLIT == 1) { row = d >> 6; scol = ((d >> 3) & 7) ^ (row & 7); }
      else                      { row = d >> 5; scol = ((d >> 3) & 3) ^ ((row >> 1) & 3); }
      lds16(src + (size_t)(g0 + row) * Kdim + kt * BK + scol * 8,
            smem + moff + d);
    }
  };
  auto ST_ALL = [&](int kt) {
    if (kt >= NT) return;
    if constexpr (SPLIT == 1) {
      STM(Ahi, m0, AOFF_H, 2, kt);
      STM(Bhi, n0, BOFF_H, 4, kt);
    } else {
      STM(Ahi, m0, AOFF_H, 1, kt);
      STM(Alo, m0, AOFF_L, 1, kt);
      STM(Bhi, n0, BOFF_H, 2, kt);
      STM(Blo, n0, BOFF_L, 2, kt);
    }
  };

  f32x4 acc[4][4] = {};

  // SPLIT=3 readers: one BK=32 k-slice, 4 frags (A rows / B cols of this wave)
  auto RD4A = [&](short8* dst, int off) {
#pragma unroll
    for (int fm = 0; fm < 4; fm++) {
      int ia = (wm*64 + fm*16 + fr)*32 + fs*8;
      dst[fm] = *(const short8*)(smem + off + swzA32(ia));
    }
  };
  auto RD4B = [&](short8* dst, int off) {
#pragma unroll
    for (int fn = 0; fn < 4; fn++) {
      int ib = (wn*64 + fn*16 + fr)*32 + fs*8;
      dst[fn] = *(const short8*)(smem + off + swzA32(ib));
    }
  };
  // SPLIT=1 readers: BK=64, frags [x][ks]
  auto RD8A = [&](short8* dst) {
#pragma unroll
    for (int fm = 0; fm < 4; fm++)
#pragma unroll
      for (int ks = 0; ks < 2; ks++) {
        int ia = (wm*64 + fm*16 + fr)*64 + ks*32 + fs*8;
        dst[fm*2+ks] = *(const short8*)(smem + AOFF_H + swzA64(ia));
      }
  };
  auto RD8B = [&](short8* dst) {
#pragma unroll
    for (int fn = 0; fn < 4; fn++)
#pragma unroll
      for (int ks = 0; ks < 2; ks++) {
        int ib = (wn*64 + fn*16 + fr)*64 + ks*32 + fs*8;
        dst[fn*2+ks] = *(const short8*)(smem + BOFF_H + swzA64(ib));
      }
  };

#define PASS44(RA, RB) do {                                                    \
  __builtin_amdgcn_s_setprio(1);                                               \
  _Pragma("unroll") for (int fm_ = 0; fm_ < 4; fm_++)                          \
    _Pragma("unroll") for (int fn_ = 0; fn_ < 4; fn_++)                        \
      acc[fm_][fn_] = __builtin_amdgcn_mfma_f32_16x16x32_bf16(                 \
          (RA)[fm_], (RB)[fn_], acc[fm_][fn_], 0, 0, 0);                       \
  __builtin_amdgcn_s_setprio(0);                                               \
} while (0)

#define PASS44K(RA, RB) do {                                                   \
  __builtin_amdgcn_s_setprio(1);                                               \
  _Pragma("unroll") for (int fm_ = 0; fm_ < 4; fm_++)                          \
    _Pragma("unroll") for (int fn_ = 0; fn_ < 4; fn_++)                        \
      _Pragma("unroll") for (int ks_ = 0; ks_ < 2; ks_++)                      \
        acc[fm_][fn_] = __builtin_amdgcn_mfma_f32_16x16x32_bf16(               \
            (RA)[fm_*2+ks_], (RB)[fn_*2+ks_], acc[fm_][fn_], 0, 0, 0);         \
  __builtin_amdgcn_s_setprio(0);                                               \
} while (0)

  // prologue: tile 0 staged and drained
  ST_ALL(0);
  VM(0); BAR();

  if constexpr (SPLIT > 1) {
    for (int T = 0; T < NT; T++) {
      short8 Ah[4], Al[4], Bh[4], Bl[4];
      RD4A(Ah, AOFF_H); RD4A(Al, AOFF_L);
      RD4B(Bh, BOFF_H); RD4B(Bl, BOFF_L);
      LGKM0();                    // reads drained into regs
      BAR();                      // all waves drained -> buffer reusable
      ST_ALL(T + 1);              // stage next tile into same buffer
      SB0();
      PASS44(Ah, Bh);             // pure-reg MFMA; stage DMA flies under
      PASS44(Ah, Bl);
      PASS44(Al, Bh);
      VM(0); BAR();               // staged data landed + visible
    }
  } else {
    for (int T = 0; T < NT; T++) {
      short8 A[8], B[8];
      RD8A(A); RD8B(B);
      LGKM0();
      BAR();
      ST_ALL(T + 1);
      SB0();
      PASS44K(A, B);
      VM(0); BAR();
    }
  }
#undef PASS44
#undef PASS44K

  const float qscale = 0.08838834764831843f; // 1/sqrt(128)
#pragma unroll
  for (int fm = 0; fm < 4; fm++)
#pragma unroll
    for (int fn = 0; fn < 4; fn++)
#pragma unroll
      for (int r = 0; r < 4; r++) {
        int gm = m0 + wm*64 + fm*16 + fs*4 + r;
        int gn = n0 + wn*64 + fn*16 + fr;
        float val = acc[fm][fn][r];
        if constexpr (EPI == 2) {
          outf[(size_t)gm * Ndim + gn] = val;
        } else {
          int b = gm >> 12, tt = gm & 4095, h = gn >> 7, dd = gn & 127;
          size_t idx = (((size_t)(b*16 + h))*4096 + tt)*128 + dd;
          if constexpr (EPI == 0) outb[idx] = f2bf(val * qscale);
          else                    outb[idx] = (val >= 0.f) ? (u16)0x3F80 : (u16)0xBF80;
        }
      }
}

// ---- pack sign bits over chunk dim: word[d] bit c = sign(k[b,h,n*64+c,d]) ----
__global__ void pack_signs(const u16* __restrict__ k, const u16* __restrict__ v,
                           unsigned long long* __restrict__ kp, unsigned long long* __restrict__ vp) {
  const int blk = blockIdx.x;            // (b*16+h)*64 + n
  const int d = threadIdx.x;             // 0..127
  const int bh = blk >> 6, n = blk & 63;
  size_t base = (((size_t)bh * 4096) + n * 64) * 128 + d;
  unsigned long long kw = 0, vw = 0;
  for (int c = 0; c < 64; c++) {
    kw |= (unsigned long long)(k[base + (size_t)c*128] >> 15) << c;
    vw |= (unsigned long long)(v[base + (size_t)c*128] >> 15) << c;
  }
  kp[(size_t)blk * 128 + d] = kw;
  vp[(size_t)blk * 128 + d] = vw;
}

// ---- parallel exact prefix-state: stride-8 int16 checkpoints + final state ----
__global__ __launch_bounds__(256) void scan_kernel(
    const unsigned long long* __restrict__ kp, const unsigned long long* __restrict__ vp,
    short* __restrict__ pfx8, float* __restrict__ fsT)
{
  const int t = threadIdx.x;
  const int bh = blockIdx.x >> 6, ep = blockIdx.x & 63;
  const int e = ep * 2 + (t >> 7), d = t & 127;
  const size_t base = (size_t)bh * 64 * 128;
  int s = 0;
  for (int n = 0; n < 64; n++) {
    if ((n & 7) == 0)
      pfx8[((size_t)(bh*8 + (n>>3))*128 + e)*128 + d] = (short)s;
    unsigned long long kw = kp[base + (size_t)n*128 + d];
    unsigned long long vw = vp[base + (size_t)n*128 + e];
    s += 64 - 2*__popcll(kw ^ vw);
  }
  fsT[((size_t)bh*128 + e)*128 + d] = (float)s;  // [bh][e][d] scratch (coalesced)
}

// ---- transpose fsT [bh][e][d] -> fstate [bh][d][e] ----
__global__ __launch_bounds__(256) void transpose_fs(const float* __restrict__ fsT,
                                                    float* __restrict__ fstate) {
  __shared__ float tile[32*130];
  const int t = threadIdx.x;
  const int bh = blockIdx.x >> 2, es = (blockIdx.x & 3) * 32;
#pragma unroll
  for (int i = 0; i < 16; i++) {
    int idx = t + i*256;
    int e2 = idx >> 7, d = idx & 127;
    tile[e2*130 + d] = fsT[((size_t)bh*128 + es + e2)*128 + d];
  }
  __syncthreads();
#pragma unroll
  for (int i = 0; i < 16; i++) {
    int idx = t + i*256;
    int d = idx >> 5, e2 = idx & 31;
    fstate[((size_t)bh*128 + d)*128 + es + e2] = tile[e2*130 + d];
  }
}

// ---- fused intra + cross per (b,h,chunk): fully parallel over 2048 blocks ----
__global__ __launch_bounds__(256) void fused_attn(
    const u16* __restrict__ q, const u16* __restrict__ k,
    const unsigned long long* __restrict__ kp, const unsigned long long* __restrict__ vp,
    const short* __restrict__ pfx8, u16* __restrict__ att)
{
  __shared__ __align__(16) u16 smem[28672];  // 56KB
  u16* sQ  = smem;          // [64][128] sw256 (q rows)
  u16* sP1 = smem + 8192;   // sK [64][128] sw256 -> sPThi [64][128] sw256
  u16* sP2 = smem + 16384;  // sVt [128][64] sw128 -> sPTlo [64][128] sw256
  u16* sS  = smem + 24576;  // [64][64] sw128

  const int t = threadIdx.x, l = t & 63, w = t >> 6;
  const int blk = blockIdx.x, bh = blk >> 6, n = blk & 63;
  const int b = bh >> 4, hh = bh & 15;
  const int fr = l & 15, fs = l >> 4;
  const size_t qbase = (((size_t)bh * 4096) + n * 64) * 128;
  const size_t pbase = (size_t)bh * 64 * 128;

  // phase A: stage Q,K (pre-swizzled source -> linear LDS dest), unpack V^T
#pragma unroll
  for (int i = 0; i < 4; i++) {
    int arow = i*16 + (t>>4);
    int aslot = (t & 15) ^ (arow & 7);
    size_t g = qbase + (size_t)arow*128 + aslot*8;
    lds16(q + g, sQ + i*2048 + t*8);
    lds16(k + g, sP1 + i*2048 + t*8);
  }
  {
    int d = t >> 1, ch = (t & 1) * 32;
    unsigned long long wv = vp[pbase + (size_t)n*128 + d];
#pragma unroll
    for (int c = 0; c < 32; c += 2) {
      uint32_t b0 = ((wv >> (ch + c)) & 1ull)     ? 0xBF80u : 0x3F80u;
      uint32_t b1 = ((wv >> (ch + c + 1)) & 1ull) ? 0xBF80u : 0x3F80u;
      int li = d*64 + ch + c;
      *(uint32_t*)(sP2 + sw128(li)) = b0 | (b1 << 16);
    }
  }
  __syncthreads();

  // phase B: scores = Q K^T, causal mask, -> sS (bf16)
  f32x4 accS[4] = {};
#pragma unroll
  for (int kk = 0; kk < 4; kk++) {
    int la = (w*16 + fr)*128 + kk*32 + fs*8;
    short8 a = *(const short8*)(sQ + sw256(la));
#pragma unroll
    for (int fn = 0; fn < 4; fn++) {
      int lb = (fn*16 + fr)*128 + kk*32 + fs*8;
      short8 bb = *(const short8*)(sP1 + sw256(lb));
      accS[fn] = __builtin_amdgcn_mfma_f32_16x16x32_bf16(a, bb, accS[fn], 0, 0, 0);
    }
  }
#pragma unroll
  for (int fn = 0; fn < 4; fn++)
#pragma unroll
    for (int r = 0; r < 4; r++) {
      int i = w*16 + fs*4 + r, j = fn*16 + fr;
      float v = (j <= i) ? accS[fn][r] : 0.f;
      sS[sw128(i*64 + j)] = f2bf(v);
    }
  __syncthreads();

  // phase C: intra = sS @ V
  f32x4 accI[8] = {};
#pragma unroll
  for (int kk = 0; kk < 2; kk++) {
    int la = (w*16 + fr)*64 + kk*32 + fs*8;
    short8 a = *(const short8*)(sS + sw128(la));
#pragma unroll
    for (int fn = 0; fn < 8; fn++) {
      int lb = (fn*16 + fr)*64 + kk*32 + fs*8;
      short8 bb = *(const short8*)(sP2 + sw128(lb));
      accI[fn] = __builtin_amdgcn_mfma_f32_16x16x32_bf16(a, bb, accI[fn], 0, 0, 0);
    }
  }
  __syncthreads();

  // cross term, two e-halves; prefix rebuilt exactly per half
  const int m0 = n & ~7, cnt = n & 7;
  for (int hf = 0; hf < 2; hf++) {
#pragma unroll
    for (int p = 0; p < 4; p++) {
      int erow = p*16 + (t>>4);
      int e = hf*64 + erow;
      const short* ps = pfx8 + ((size_t)(bh*8 + (n>>3))*128 + e)*128 + (t&15)*8;
      short8 pv = *(const short8*)ps;
      int accj[8];
#pragma unroll
      for (int j = 0; j < 8; j++) accj[j] = pv[j];
      for (int m = 0; m < cnt; m++) {
        unsigned long long vw = vp[pbase + (size_t)(m0+m)*128 + e];
#pragma unroll
        for (int j = 0; j < 8; j++) {
          unsigned long long kw = kp[pbase + (size_t)(m0+m)*128 + (t&15)*8 + j];
          accj[j] += 64 - 2*__popcll(kw ^ vw);
        }
      }
      short8 hi, lo;
#pragma unroll
      for (int j = 0; j < 8; j++) {
        hi[j] = (short)f2bf((float)(accj[j] >> 5));
        lo[j] = (short)f2bf((float)(accj[j] & 31));
      }
      int pi = sw256(erow*128 + (t&15)*8);
      *(short8*)(sP1 + pi) = hi;
      *(short8*)(sP2 + pi) = lo;
    }
    __syncthreads();

    f32x4 acch[4] = {}, accl[4] = {};
#pragma unroll
    for (int kk = 0; kk < 4; kk++) {
      int la = (w*16 + fr)*128 + kk*32 + fs*8;
      short8 a = *(const short8*)(sQ + sw256(la));
#pragma unroll
      for (int fn = 0; fn < 4; fn++) {
        int pb = sw256((fn*16 + fr)*128 + kk*32 + fs*8);
        acch[fn] = __builtin_amdgcn_mfma_f32_16x16x32_bf16(a, *(const short8*)(sP1 + pb), acch[fn], 0, 0, 0);
        accl[fn] = __builtin_amdgcn_mfma_f32_16x16x32_bf16(a, *(const short8*)(sP2 + pb), accl[fn], 0, 0, 0);
      }
    }
#pragma unroll
    for (int fn = 0; fn < 4; fn++)
#pragma unroll
      for (int r = 0; r < 4; r++) {
        int c = w*16 + fs*4 + r;
        int dcol = hf*64 + fn*16 + fr;
        float val = accI[hf*4+fn][r] + 32.f*acch[fn][r] + accl[fn][r];
        size_t idx = ((size_t)(b*4096 + n*64 + c))*2048 + hh*128 + dcol;
        att[idx] = f2bf(val);
      }
    __syncthreads();  // before next half overwrites sP1/sP2
  }
}

extern "C" void kernel_launch(void* const* d_in, const int* in_sizes, int n_in,
                              void* d_out, int out_size, void* d_ws, size_t ws_size,
                              hipStream_t stream) {
  (void)in_sizes; (void)n_in; (void)out_size; (void)ws_size;
  const float* x  = (const float*)d_in[0];
  const float* Wq = (const float*)d_in[1];
  const float* Wk = (const float*)d_in[2];
  const float* Wv = (const float*)d_in[3];
  const float* Wo = (const float*)d_in[4];
  float* out = (float*)d_out;
  float* fstate = out + (size_t)16777216; // B*T*D

  char* ws = (char*)d_ws;
  u16* x_hi = (u16*)(ws + 0);           // later aliased as att
  u16* x_lo = (u16*)(ws + 33554432);    // later aliased as fsT
  u16* qb   = (u16*)(ws + 67108864);
  u16* kb   = (u16*)(ws + 100663296);
  u16* vb   = (u16*)(ws + 134217728);   // later aliased as pfx8
  u16* wq_h = (u16*)(ws + 167772160);
  u16* wk_h = (u16*)(ws + 176160768);
  u16* wk_l = (u16*)(ws + 184549376);
  u16* wv_h = (u16*)(ws + 192937984);
  u16* wv_l = (u16*)(ws + 201326592);
  u16* wo_h = (u16*)(ws + 209715200);
  unsigned long long* kpk = (unsigned long long*)(ws + 218103808);
  unsigned long long* vpk = (unsigned long long*)(ws + 220200960);
  u16* att    = x_hi;                   // x_hi dead after projections
  float* fsT  = (float*)(ws + 33554432);// x_lo dead after K/V gemms
  short* pfx8 = (short*)(ws + 134217728); // vb dead after pack_signs

  split_kernel<<<2048, 256, 0, stream>>>(x,  x_hi, x_lo, 16777216);
  split_kernel<<<1024, 256, 0, stream>>>(Wq, wq_h, nullptr, 4194304);
  split_kernel<<<1024, 256, 0, stream>>>(Wk, wk_h, wk_l, 4194304);
  split_kernel<<<1024, 256, 0, stream>>>(Wv, wv_h, wv_l, 4194304);
  split_kernel<<<1024, 256, 0, stream>>>(Wo, wo_h, nullptr, 4194304);

  gemm8p<1,0><<<512, 512, 0, stream>>>(x_hi, nullptr, wq_h, nullptr, qb, nullptr, 8192, 2048, 2048);
  gemm8p<3,1><<<512, 512, 0, stream>>>(x_hi, x_lo, wk_h, wk_l, kb, nullptr, 8192, 2048, 2048);
  gemm8p<3,1><<<512, 512, 0, stream>>>(x_hi, x_lo, wv_h, wv_l, vb, nullptr, 8192, 2048, 2048);

  pack_signs<<<2048, 128, 0, stream>>>(kb, vb, kpk, vpk);
  scan_kernel<<<2048, 256, 0, stream>>>(kpk, vpk, pfx8, fsT);
  transpose_fs<<<128, 256, 0, stream>>>(fsT, fstate);
  fused_attn<<<2048, 256, 0, stream>>>(qb, kb, kpk, vpk, pfx8, att);

  gemm8p<1,2><<<512, 512, 0, stream>>>(att, nullptr, wo_h, nullptr, nullptr, out, 8192, 2048, 2048);
}

// Round 12
// 668.860 us; speedup vs baseline: 2.9914x; 2.9914x over previous
//
#include <hip/hip_runtime.h>
#include <stdint.h>

typedef __attribute__((ext_vector_type(8))) short short8;
typedef __attribute__((ext_vector_type(4))) float f32x4;
typedef unsigned short u16;

// ---- helpers ----
__device__ __forceinline__ u16 f2bf(float f) {
  uint32_t u = __builtin_bit_cast(uint32_t, f);
  u = (u + 0x7FFFu + ((u >> 16) & 1u)) >> 16;
  return (u16)u;
}
__device__ __forceinline__ float bf2f(u16 h) {
  uint32_t u = ((uint32_t)h) << 16;
  return __builtin_bit_cast(float, u);
}
__device__ __forceinline__ void lds16(const u16* g, u16* l) {
  __builtin_amdgcn_global_load_lds(
      (const __attribute__((address_space(1))) void*)g,
      (__attribute__((address_space(3))) void*)l, 16, 0, 0);
}
// LDS XOR swizzles on u16 indices (16B granule): involutions.
__device__ __forceinline__ int sw256(int i) { return i ^ (((i >> 7) & 7) << 3); }
__device__ __forceinline__ int sw128(int i) { return i ^ (((i >> 6) & 7) << 3); }
// tile-row swizzles: BK=64 rows: flip slot bits[5:3] by row&7
__device__ __forceinline__ int swzA64(int i) { return i ^ (((i >> 6) & 7) << 3); }
// BK=32 rows: flip slot bits[4:3] by (row>>1)&3
__device__ __forceinline__ int swzA32(int i) { return i ^ (((i >> 6) & 3) << 3); }

#define SB0() __builtin_amdgcn_sched_barrier(0)
#define BAR() __builtin_amdgcn_s_barrier()
#define LGKM0() do { asm volatile("s_waitcnt lgkmcnt(0)" ::: "memory"); SB0(); } while (0)
#define VM(n) asm volatile("s_waitcnt vmcnt(" #n ")" ::: "memory")
#define VMNOP do {} while (0)

// ---- fused vectorized split: f32 -> bf16 hi (+ optional lo), all 5 inputs ----
__global__ __launch_bounds__(256) void split_all(
    const float* __restrict__ x,  const float* __restrict__ Wq,
    const float* __restrict__ Wk, const float* __restrict__ Wv,
    const float* __restrict__ Wo,
    u16* __restrict__ xh, u16* __restrict__ xl,
    u16* __restrict__ qh, u16* __restrict__ kh, u16* __restrict__ kl,
    u16* __restrict__ vh, u16* __restrict__ vl, u16* __restrict__ oh)
{
  const int bid = blockIdx.x, t = threadIdx.x;
  if (bid < 2048) {
    // x: 16777216 elems = 2097152 vec8 (hi + lo)
    for (int i = bid * 256 + t; i < 2097152; i += 2048 * 256) {
      const float4* s = (const float4*)x + 2 * (size_t)i;
      float4 a = s[0], b = s[1];
      float v[8] = {a.x, a.y, a.z, a.w, b.x, b.y, b.z, b.w};
      short8 hi, lo;
#pragma unroll
      for (int j = 0; j < 8; j++) {
        u16 h = f2bf(v[j]);
        hi[j] = (short)h;
        lo[j] = (short)f2bf(v[j] - bf2f(h));
      }
      ((short8*)xh)[i] = hi;
      ((short8*)xl)[i] = lo;
    }
  } else {
    const int seg = (bid - 2048) >> 9;      // 0..3 : Wq, Wk, Wv, Wo
    const int sb  = (bid - 2048) & 511;
    const float* W = seg == 0 ? Wq : seg == 1 ? Wk : seg == 2 ? Wv : Wo;
    u16* H = seg == 0 ? qh : seg == 1 ? kh : seg == 2 ? vh : oh;
    u16* L = seg == 1 ? kl : seg == 2 ? vl : nullptr;
    // 4194304 elems = 524288 vec8 each
    for (int i = sb * 256 + t; i < 524288; i += 512 * 256) {
      const float4* s = (const float4*)W + 2 * (size_t)i;
      float4 a = s[0], b = s[1];
      float v[8] = {a.x, a.y, a.z, a.w, b.x, b.y, b.z, b.w};
      short8 hi, lo;
#pragma unroll
      for (int j = 0; j < 8; j++) {
        u16 h = f2bf(v[j]);
        hi[j] = (short)h;
        lo[j] = (short)f2bf(v[j] - bf2f(h));
      }
      ((short8*)H)[i] = hi;
      if (L) ((short8*)L)[i] = lo;
    }
  }
}

// ==== 256x256 GEMM with counted-vmcnt deep pipeline (R7 config, best=683us) ====
// 8 waves (2M x 4N), per-wave 128x64 out. Tile T+1 staged in 8KB rounds
// DURING tile T's phases; phase-end s_waitcnt vmcnt(N) counts so staged
// loads stay in flight across raw s_barriers (never drains mid-loop).
// SPLIT=1: BK=64, 4 quadrant phases (16 MFMA each), waits vmcnt(4)@phi1,
//          vmcnt(2)@phi3. SPLIT=3: BK=32, 3 pass-phases (32 MFMA each:
//          hi*hi, hi*lo, lo*hi), waits vmcnt(6)/(6)/(4). Last tile peeled.
// EPI 0: bf16 (b,h,t,d), *qscale | EPI 1: sign->+-1 bf16 (b,h,t,d) | EPI 2: f32 MxN
template<int SPLIT, int EPI>
__global__ __launch_bounds__(512, 2) void gemm8p(
    const u16* __restrict__ Ahi, const u16* __restrict__ Alo,
    const u16* __restrict__ Bhi, const u16* __restrict__ Blo,
    u16* __restrict__ outb, float* __restrict__ outf,
    int Mdim, int Ndim, int Kdim)
{
  constexpr int BK   = (SPLIT > 1) ? 32 : 64;
  constexpr int TILE = 256 * BK;                 // u16 per matrix tile
  constexpr int NMAT = (SPLIT > 1) ? 4 : 2;
  constexpr int AOFF_H = 0;
  constexpr int AOFF_L = (SPLIT > 1) ? TILE : 0;
  constexpr int BOFF_H = (SPLIT > 1) ? 2*TILE : TILE;
  constexpr int BOFF_L = (SPLIT > 1) ? 3*TILE : 0;
  __shared__ __align__(16) u16 smem[2 * NMAT * TILE];   // 128 KiB

  const int t = threadIdx.x, l = t & 63;
  const int w = t >> 6;
  const int wm = w >> 2, wn = w & 3;
  const int fr = l & 15, fs = l >> 4;
  // XCD-bijective block swizzle (256 blocks % 8 == 0)
  const int sb = (blockIdx.x & 7) * 32 + (blockIdx.x >> 3);
  const int m0 = (sb >> 3) * 256, n0 = (sb & 7) * 256;
  const int NT = Kdim / BK;

  // stage one 8KB round (512 lanes x 16B) of matrix `src` for K-tile kt.
  auto ST = [&](const u16* src, int g0, int moff, int kt, int r) {
    if (kt >= NT) return;
    const int bufb = (kt & 1) * NMAT * TILE;
    int d = r * 4096 + t * 8;
    int row, scol;
    if constexpr (SPLIT == 1) { row = d >> 6; scol = ((d >> 3) & 7) ^ (row & 7); }
    else                      { row = d >> 5; scol = ((d >> 3) & 3) ^ ((row >> 1) & 3); }
    lds16(src + (size_t)(g0 + row) * Kdim + kt * BK + scol * 8,
          smem + bufb + moff + d);
  };

  f32x4 acc[8][4] = {};

#define SWZ(i) ((BK == 64) ? swzA64(i) : swzA32(i))
  // SPLIT=3 readers (one 32-k-slice)
  auto RD8 = [&](short8* dst, int bufb, int off) {
#pragma unroll
    for (int fm = 0; fm < 8; fm++) {
      int ia = (wm*128 + fm*16 + fr)*BK + fs*8;
      dst[fm] = *(const short8*)(smem + bufb + off + SWZ(ia));
    }
  };
  auto RD4 = [&](short8* dst, int bufb, int off) {
#pragma unroll
    for (int fn = 0; fn < 4; fn++) {
      int ib = (wn*64 + fn*16 + fr)*BK + fs*8;
      dst[fn] = *(const short8*)(smem + bufb + off + SWZ(ib));
    }
  };
  // SPLIT=1 readers
  auto RDQ = [&](short8* dst, int bufb, int q) {   // A quadrant q: [i*2+ks]
#pragma unroll
    for (int i = 0; i < 2; i++)
#pragma unroll
      for (int ks = 0; ks < 2; ks++) {
        int ia = (wm*128 + (2*q+i)*16 + fr)*64 + ks*32 + fs*8;
        dst[i*2+ks] = *(const short8*)(smem + bufb + AOFF_H + swzA64(ia));
      }
  };
  auto RDB8 = [&](short8* dst, int bufb) {         // B full: [fn*2+ks]
#pragma unroll
    for (int fn = 0; fn < 4; fn++)
#pragma unroll
      for (int ks = 0; ks < 2; ks++) {
        int ib = (wn*64 + fn*16 + fr)*64 + ks*32 + fs*8;
        dst[fn*2+ks] = *(const short8*)(smem + bufb + BOFF_H + swzA64(ib));
      }
  };

#define PASS32(RA, RB) do {                                                    \
  __builtin_amdgcn_s_setprio(1);                                               \
  _Pragma("unroll") for (int fm_ = 0; fm_ < 8; fm_++)                          \
    _Pragma("unroll") for (int fn_ = 0; fn_ < 4; fn_++)                        \
      acc[fm_][fn_] = __builtin_amdgcn_mfma_f32_16x16x32_bf16(                 \
          (RA)[fm_], (RB)[fn_], acc[fm_][fn_], 0, 0, 0);                       \
  __builtin_amdgcn_s_setprio(0);                                               \
  SB0();                                                                       \
} while (0)

#define PASS16(Q, AQ, BB) do {                                                 \
  __builtin_amdgcn_s_setprio(1);                                               \
  _Pragma("unroll") for (int i_ = 0; i_ < 2; i_++)                             \
    _Pragma("unroll") for (int fn_ = 0; fn_ < 4; fn_++)                        \
      _Pragma("unroll") for (int ks_ = 0; ks_ < 2; ks_++)                      \
        acc[2*(Q)+i_][fn_] = __builtin_amdgcn_mfma_f32_16x16x32_bf16(          \
            (AQ)[i_*2+ks_], (BB)[fn_*2+ks_], acc[2*(Q)+i_][fn_], 0, 0, 0);     \
  __builtin_amdgcn_s_setprio(0);                                               \
  SB0();                                                                       \
} while (0)

// SPLIT=3 tile: 3 phases, stage T+1 rounds Ah,Ah,Bh,Bh | Bl,Bl | Al,Al
#define T3BODY(T, W0, W1, W2) {                                                \
  const int bufb = ((T) & 1) * NMAT * TILE;                                    \
  short8 xah[8], xbh[4], xbl[4], xal[8];                                       \
  RD8(xah, bufb, AOFF_H); RD4(xbh, bufb, BOFF_H);                              \
  ST(Ahi, m0, AOFF_H, (T)+1, 0); ST(Ahi, m0, AOFF_H, (T)+1, 1);                \
  ST(Bhi, n0, BOFF_H, (T)+1, 0); ST(Bhi, n0, BOFF_H, (T)+1, 1);                \
  W0; BAR(); LGKM0(); PASS32(xah, xbh); BAR();                                 \
  RD4(xbl, bufb, BOFF_L);                                                      \
  ST(Blo, n0, BOFF_L, (T)+1, 0); ST(Blo, n0, BOFF_L, (T)+1, 1);                \
  W1; BAR(); LGKM0(); PASS32(xah, xbl); BAR();                                 \
  RD8(xal, bufb, AOFF_L);                                                      \
  ST(Alo, m0, AOFF_L, (T)+1, 0); ST(Alo, m0, AOFF_L, (T)+1, 1);                \
  W2; BAR(); LGKM0(); PASS32(xal, xbh); BAR();                                 \
}

// SPLIT=1 tile: 4 quadrant phases, stage T+1 rounds B0,B1 | B2,B3 | A0,A2 | A1,A3
#define T1BODY(T, W1, W3) {                                                    \
  const int bufb = ((T) & 1) * NMAT * TILE;                                    \
  short8 bb[8], aq[4];                                                         \
  RDB8(bb, bufb); RDQ(aq, bufb, 0);                                            \
  ST(Bhi, n0, BOFF_H, (T)+1, 0); ST(Bhi, n0, BOFF_H, (T)+1, 1);                \
  BAR(); LGKM0(); PASS16(0, aq, bb); BAR();                                    \
  RDQ(aq, bufb, 1);                                                            \
  ST(Bhi, n0, BOFF_H, (T)+1, 2); ST(Bhi, n0, BOFF_H, (T)+1, 3);                \
  W1; BAR(); LGKM0(); PASS16(1, aq, bb); BAR();                                \
  RDQ(aq, bufb, 2);                                                            \
  ST(Ahi, m0, AOFF_H, (T)+1, 0); ST(Ahi, m0, AOFF_H, (T)+1, 2);                \
  BAR(); LGKM0(); PASS16(2, aq, bb); BAR();                                    \
  RDQ(aq, bufb, 3);                                                            \
  ST(Ahi, m0, AOFF_H, (T)+1, 1); ST(Ahi, m0, AOFF_H, (T)+1, 3);                \
  W3; BAR(); LGKM0(); PASS16(3, aq, bb); BAR();                                \
}

  if constexpr (SPLIT > 1) {
    // prologue: T0 fully staged; Ah,Bh landed, Bl,Al (4) left in flight
    ST(Ahi, m0, AOFF_H, 0, 0); ST(Ahi, m0, AOFF_H, 0, 1);
    ST(Bhi, n0, BOFF_H, 0, 0); ST(Bhi, n0, BOFF_H, 0, 1);
    ST(Blo, n0, BOFF_L, 0, 0); ST(Blo, n0, BOFF_L, 0, 1);
    ST(Alo, m0, AOFF_L, 0, 0); ST(Alo, m0, AOFF_L, 0, 1);
    VM(4); BAR();
    for (int T = 0; T < NT - 1; T++) T3BODY(T, VM(6), VM(6), VM(4))
    T3BODY(NT - 1, VM(2), VM(0), VMNOP)
  } else {
    // prologue: T0 staged; Ar1,Ar3 (2) left in flight
    ST(Bhi, n0, BOFF_H, 0, 0); ST(Bhi, n0, BOFF_H, 0, 1);
    ST(Bhi, n0, BOFF_H, 0, 2); ST(Bhi, n0, BOFF_H, 0, 3);
    ST(Ahi, m0, AOFF_H, 0, 0); ST(Ahi, m0, AOFF_H, 0, 2);
    ST(Ahi, m0, AOFF_H, 0, 1); ST(Ahi, m0, AOFF_H, 0, 3);
    VM(2); BAR();
    for (int T = 0; T < NT - 1; T++) T1BODY(T, VM(4), VM(2))
    T1BODY(NT - 1, VM(0), VMNOP)
  }
#undef SWZ
#undef T3BODY
#undef T1BODY
#undef PASS32
#undef PASS16

  const float qscale = 0.08838834764831843f; // 1/sqrt(128)
#pragma unroll
  for (int fm = 0; fm < 8; fm++)
#pragma unroll
    for (int fn = 0; fn < 4; fn++)
#pragma unroll
      for (int r = 0; r < 4; r++) {
        int gm = m0 + wm*128 + fm*16 + fs*4 + r;
        int gn = n0 + wn*64 + fn*16 + fr;
        float val = acc[fm][fn][r];
        if constexpr (EPI == 2) {
          outf[(size_t)gm * Ndim + gn] = val;
        } else {
          int b = gm >> 12, tt = gm & 4095, h = gn >> 7, dd = gn & 127;
          size_t idx = (((size_t)(b*16 + h))*4096 + tt)*128 + dd;
          if constexpr (EPI == 0) outb[idx] = f2bf(val * qscale);
          else                    outb[idx] = (val >= 0.f) ? (u16)0x3F80 : (u16)0xBF80;
        }
      }
}

// ---- pack sign bits over chunk dim: word[d] bit c = sign(k[b,h,n*64+c,d]) ----
__global__ void pack_signs(const u16* __restrict__ k, const u16* __restrict__ v,
                           unsigned long long* __restrict__ kp, unsigned long long* __restrict__ vp) {
  const int blk = blockIdx.x;            // (b*16+h)*64 + n
  const int d = threadIdx.x;             // 0..127
  const int bh = blk >> 6, n = blk & 63;
  size_t base = (((size_t)bh * 4096) + n * 64) * 128 + d;
  unsigned long long kw = 0, vw = 0;
  for (int c = 0; c < 64; c++) {
    kw |= (unsigned long long)(k[base + (size_t)c*128] >> 15) << c;
    vw |= (unsigned long long)(v[base + (size_t)c*128] >> 15) << c;
  }
  kp[(size_t)blk * 128 + d] = kw;
  vp[(size_t)blk * 128 + d] = vw;
}

// ---- parallel exact prefix-state: stride-8 int16 checkpoints + final state ----
__global__ __launch_bounds__(256) void scan_kernel(
    const unsigned long long* __restrict__ kp, const unsigned long long* __restrict__ vp,
    short* __restrict__ pfx8, float* __restrict__ fsT)
{
  const int t = threadIdx.x;
  const int bh = blockIdx.x >> 6, ep = blockIdx.x & 63;
  const int e = ep * 2 + (t >> 7), d = t & 127;
  const size_t base = (size_t)bh * 64 * 128;
  int s = 0;
  for (int n = 0; n < 64; n++) {
    if ((n & 7) == 0)
      pfx8[((size_t)(bh*8 + (n>>3))*128 + e)*128 + d] = (short)s;
    unsigned long long kw = kp[base + (size_t)n*128 + d];
    unsigned long long vw = vp[base + (size_t)n*128 + e];
    s += 64 - 2*__popcll(kw ^ vw);
  }
  fsT[((size_t)bh*128 + e)*128 + d] = (float)s;  // [bh][e][d] scratch (coalesced)
}

// ---- transpose fsT [bh][e][d] -> fstate [bh][d][e] ----
__global__ __launch_bounds__(256) void transpose_fs(const float* __restrict__ fsT,
                                                    float* __restrict__ fstate) {
  __shared__ float tile[32*130];
  const int t = threadIdx.x;
  const int bh = blockIdx.x >> 2, es = (blockIdx.x & 3) * 32;
#pragma unroll
  for (int i = 0; i < 16; i++) {
    int idx = t + i*256;
    int e2 = idx >> 7, d = idx & 127;
    tile[e2*130 + d] = fsT[((size_t)bh*128 + es + e2)*128 + d];
  }
  __syncthreads();
#pragma unroll
  for (int i = 0; i < 16; i++) {
    int idx = t + i*256;
    int d = idx >> 5, e2 = idx & 31;
    fstate[((size_t)bh*128 + d)*128 + es + e2] = tile[e2*130 + d];
  }
}

// ---- fused intra + cross per (b,h,chunk): fully parallel over 2048 blocks ----
__global__ __launch_bounds__(256) void fused_attn(
    const u16* __restrict__ q, const u16* __restrict__ k,
    const unsigned long long* __restrict__ kp, const unsigned long long* __restrict__ vp,
    const short* __restrict__ pfx8, u16* __restrict__ att)
{
  __shared__ __align__(16) u16 smem[28672];  // 56KB
  u16* sQ  = smem;          // [64][128] sw256 (q rows)
  u16* sP1 = smem + 8192;   // sK [64][128] sw256 -> sPThi [64][128] sw256
  u16* sP2 = smem + 16384;  // sVt [128][64] sw128 -> sPTlo [64][128] sw256
  u16* sS  = smem + 24576;  // [64][64] sw128

  const int t = threadIdx.x, l = t & 63, w = t >> 6;
  const int blk = blockIdx.x, bh = blk >> 6, n = blk & 63;
  const int b = bh >> 4, hh = bh & 15;
  const int fr = l & 15, fs = l >> 4;
  const size_t qbase = (((size_t)bh * 4096) + n * 64) * 128;
  const size_t pbase = (size_t)bh * 64 * 128;

  // phase A: stage Q,K (pre-swizzled source -> linear LDS dest), unpack V^T
#pragma unroll
  for (int i = 0; i < 4; i++) {
    int arow = i*16 + (t>>4);
    int aslot = (t & 15) ^ (arow & 7);
    size_t g = qbase + (size_t)arow*128 + aslot*8;
    lds16(q + g, sQ + i*2048 + t*8);
    lds16(k + g, sP1 + i*2048 + t*8);
  }
  {
    int d = t >> 1, ch = (t & 1) * 32;
    unsigned long long wv = vp[pbase + (size_t)n*128 + d];
#pragma unroll
    for (int c = 0; c < 32; c += 2) {
      uint32_t b0 = ((wv >> (ch + c)) & 1ull)     ? 0xBF80u : 0x3F80u;
      uint32_t b1 = ((wv >> (ch + c + 1)) & 1ull) ? 0xBF80u : 0x3F80u;
      int li = d*64 + ch + c;
      *(uint32_t*)(sP2 + sw128(li)) = b0 | (b1 << 16);
    }
  }
  __syncthreads();

  // phase B: scores = Q K^T, causal mask, -> sS (bf16)
  f32x4 accS[4] = {};
#pragma unroll
  for (int kk = 0; kk < 4; kk++) {
    int la = (w*16 + fr)*128 + kk*32 + fs*8;
    short8 a = *(const short8*)(sQ + sw256(la));
#pragma unroll
    for (int fn = 0; fn < 4; fn++) {
      int lb = (fn*16 + fr)*128 + kk*32 + fs*8;
      short8 bb = *(const short8*)(sP1 + sw256(lb));
      accS[fn] = __builtin_amdgcn_mfma_f32_16x16x32_bf16(a, bb, accS[fn], 0, 0, 0);
    }
  }
#pragma unroll
  for (int fn = 0; fn < 4; fn++)
#pragma unroll
    for (int r = 0; r < 4; r++) {
      int i = w*16 + fs*4 + r, j = fn*16 + fr;
      float v = (j <= i) ? accS[fn][r] : 0.f;
      sS[sw128(i*64 + j)] = f2bf(v);
    }
  __syncthreads();

  // phase C: intra = sS @ V
  f32x4 accI[8] = {};
#pragma unroll
  for (int kk = 0; kk < 2; kk++) {
    int la = (w*16 + fr)*64 + kk*32 + fs*8;
    short8 a = *(const short8*)(sS + sw128(la));
#pragma unroll
    for (int fn = 0; fn < 8; fn++) {
      int lb = (fn*16 + fr)*64 + kk*32 + fs*8;
      short8 bb = *(const short8*)(sP2 + sw128(lb));
      accI[fn] = __builtin_amdgcn_mfma_f32_16x16x32_bf16(a, bb, accI[fn], 0, 0, 0);
    }
  }
  __syncthreads();

  // cross term, two e-halves; prefix rebuilt exactly per half
  const int m0 = n & ~7, cnt = n & 7;
  for (int hf = 0; hf < 2; hf++) {
#pragma unroll
    for (int p = 0; p < 4; p++) {
      int erow = p*16 + (t>>4);
      int e = hf*64 + erow;
      const short* ps = pfx8 + ((size_t)(bh*8 + (n>>3))*128 + e)*128 + (t&15)*8;
      short8 pv = *(const short8*)ps;
      int accj[8];
#pragma unroll
      for (int j = 0; j < 8; j++) accj[j] = pv[j];
      for (int m = 0; m < cnt; m++) {
        unsigned long long vw = vp[pbase + (size_t)(m0+m)*128 + e];
#pragma unroll
        for (int j = 0; j < 8; j++) {
          unsigned long long kw = kp[pbase + (size_t)(m0+m)*128 + (t&15)*8 + j];
          accj[j] += 64 - 2*__popcll(kw ^ vw);
        }
      }
      short8 hi, lo;
#pragma unroll
      for (int j = 0; j < 8; j++) {
        hi[j] = (short)f2bf((float)(accj[j] >> 5));
        lo[j] = (short)f2bf((float)(accj[j] & 31));
      }
      int pi = sw256(erow*128 + (t&15)*8);
      *(short8*)(sP1 + pi) = hi;
      *(short8*)(sP2 + pi) = lo;
    }
    __syncthreads();

    f32x4 acch[4] = {}, accl[4] = {};
#pragma unroll
    for (int kk = 0; kk < 4; kk++) {
      int la = (w*16 + fr)*128 + kk*32 + fs*8;
      short8 a = *(const short8*)(sQ + sw256(la));
#pragma unroll
      for (int fn = 0; fn < 4; fn++) {
        int pb = sw256((fn*16 + fr)*128 + kk*32 + fs*8);
        acch[fn] = __builtin_amdgcn_mfma_f32_16x16x32_bf16(a, *(const short8*)(sP1 + pb), acch[fn], 0, 0, 0);
        accl[fn] = __builtin_amdgcn_mfma_f32_16x16x32_bf16(a, *(const short8*)(sP2 + pb), accl[fn], 0, 0, 0);
      }
    }
#pragma unroll
    for (int fn = 0; fn < 4; fn++)
#pragma unroll
      for (int r = 0; r < 4; r++) {
        int c = w*16 + fs*4 + r;
        int dcol = hf*64 + fn*16 + fr;
        float val = accI[hf*4+fn][r] + 32.f*acch[fn][r] + accl[fn][r];
        size_t idx = ((size_t)(b*4096 + n*64 + c))*2048 + hh*128 + dcol;
        att[idx] = f2bf(val);
      }
    __syncthreads();  // before next half overwrites sP1/sP2
  }
}

extern "C" void kernel_launch(void* const* d_in, const int* in_sizes, int n_in,
                              void* d_out, int out_size, void* d_ws, size_t ws_size,
                              hipStream_t stream) {
  (void)in_sizes; (void)n_in; (void)out_size; (void)ws_size;
  const float* x  = (const float*)d_in[0];
  const float* Wq = (const float*)d_in[1];
  const float* Wk = (const float*)d_in[2];
  const float* Wv = (const float*)d_in[3];
  const float* Wo = (const float*)d_in[4];
  float* out = (float*)d_out;
  float* fstate = out + (size_t)16777216; // B*T*D

  char* ws = (char*)d_ws;
  u16* x_hi = (u16*)(ws + 0);           // later aliased as att
  u16* x_lo = (u16*)(ws + 33554432);    // later aliased as fsT
  u16* qb   = (u16*)(ws + 67108864);
  u16* kb   = (u16*)(ws + 100663296);
  u16* vb   = (u16*)(ws + 134217728);   // later aliased as pfx8
  u16* wq_h = (u16*)(ws + 167772160);
  u16* wk_h = (u16*)(ws + 176160768);
  u16* wk_l = (u16*)(ws + 184549376);
  u16* wv_h = (u16*)(ws + 192937984);
  u16* wv_l = (u16*)(ws + 201326592);
  u16* wo_h = (u16*)(ws + 209715200);
  unsigned long long* kpk = (unsigned long long*)(ws + 218103808);
  unsigned long long* vpk = (unsigned long long*)(ws + 220200960);
  u16* att    = x_hi;                   // x_hi dead after projections
  float* fsT  = (float*)(ws + 33554432);// x_lo dead after K/V gemms
  short* pfx8 = (short*)(ws + 134217728); // vb dead after pack_signs

  split_all<<<4096, 256, 0, stream>>>(x, Wq, Wk, Wv, Wo,
                                      x_hi, x_lo, wq_h, wk_h, wk_l, wv_h, wv_l, wo_h);

  gemm8p<1,0><<<256, 512, 0, stream>>>(x_hi, nullptr, wq_h, nullptr, qb, nullptr, 8192, 2048, 2048);
  gemm8p<3,1><<<256, 512, 0, stream>>>(x_hi, x_lo, wk_h, wk_l, kb, nullptr, 8192, 2048, 2048);
  gemm8p<3,1><<<256, 512, 0, stream>>>(x_hi, x_lo, wv_h, wv_l, vb, nullptr, 8192, 2048, 2048);

  pack_signs<<<2048, 128, 0, stream>>>(kb, vb, kpk, vpk);
  scan_kernel<<<2048, 256, 0, stream>>>(kpk, vpk, pfx8, fsT);
  transpose_fs<<<128, 256, 0, stream>>>(fsT, fstate);
  fused_attn<<<2048, 256, 0, stream>>>(qb, kb, kpk, vpk, pfx8, att);

  gemm8p<1,2><<<256, 512, 0, stream>>>(att, nullptr, wo_h, nullptr, nullptr, out, 8192, 2048, 2048);
}